// Round 1
// baseline (36821.960 us; speedup 1.0000x reference)
//
#include <hip/hip_runtime.h>
#include <hip/hip_bf16.h>

// Problem dims
#define TT    2048
#define DD    1024
#define HH    2048
#define TAGS_ 1024
#define G4    8192   // 4*H

typedef float f32x4 __attribute__((ext_vector_type(4)));
typedef __bf16 bf16x8 __attribute__((ext_vector_type(8)));

__device__ __forceinline__ unsigned short f2bf(float f) {
    unsigned u = __float_as_uint(f);
    unsigned r = (u + 0x7fffu + ((u >> 16) & 1u)) >> 16;
    return (unsigned short)r;
}

__device__ __forceinline__ void unpack8(uint4 v, float* h) {
    h[0] = __uint_as_float(v.x << 16); h[1] = __uint_as_float(v.x & 0xffff0000u);
    h[2] = __uint_as_float(v.y << 16); h[3] = __uint_as_float(v.y & 0xffff0000u);
    h[4] = __uint_as_float(v.z << 16); h[5] = __uint_as_float(v.z & 0xffff0000u);
    h[6] = __uint_as_float(v.w << 16); h[7] = __uint_as_float(v.w & 0xffff0000u);
}

// ---------------- fp32 -> bf16 convert ----------------
__global__ __launch_bounds__(256) void cvt_bf16_k(const float* __restrict__ in,
                                                  unsigned short* __restrict__ out, int n) {
    int i = (blockIdx.x * 256 + threadIdx.x) * 4;
    if (i < n) {
        float4 v = *(const float4*)(in + i);
        ushort4 o;
        o.x = f2bf(v.x); o.y = f2bf(v.y); o.z = f2bf(v.z); o.w = f2bf(v.w);
        *(ushort4*)(out + i) = o;
    }
}

// ---------------- bf16 MFMA GEMM: C[M][N] = A[M][K] * B[N][K]^T + bias ----------------
// 128x128 tile, 4 waves (2x2), each wave 64x64 via 4x4 frags of 16x16x32.
__global__ __launch_bounds__(256) void gemm_bt_k(const unsigned short* __restrict__ A,
                                                 const unsigned short* __restrict__ B,
                                                 float* __restrict__ C,
                                                 const float* __restrict__ bias1,
                                                 const float* __restrict__ bias2,
                                                 int M, int N, int K) {
    const int bn = blockIdx.x, bm = blockIdx.y;
    const int tid = threadIdx.x;
    const int wave = tid >> 6, lane = tid & 63;
    const int wm = (wave >> 1) * 64, wn = (wave & 1) * 64;

    __shared__ unsigned short As[128 * 64];
    __shared__ unsigned short Bs[128 * 64];

    f32x4 acc[4][4] = {};

    for (int k0 = 0; k0 < K; k0 += 64) {
        // stage 128x64 bf16 tiles (16 KiB each) via 16B reg copies
#pragma unroll
        for (int i = 0; i < 4; ++i) {
            int bo = (tid + i * 256) * 16;     // byte offset within tile
            int r = bo >> 7;                   // row (128B per row)
            int cb = bo & 127;                 // col byte
            *(uint4*)((char*)As + bo) =
                *(const uint4*)((const char*)(A + (size_t)(bm * 128 + r) * K + k0) + cb);
            *(uint4*)((char*)Bs + bo) =
                *(const uint4*)((const char*)(B + (size_t)(bn * 128 + r) * K + k0) + cb);
        }
        __syncthreads();
#pragma unroll
        for (int kk = 0; kk < 64; kk += 32) {
            int kb = kk + (lane >> 4) * 8;
            bf16x8 af[4], bfr[4];
#pragma unroll
            for (int mi = 0; mi < 4; ++mi)
                af[mi] = *(const bf16x8*)&As[(wm + mi * 16 + (lane & 15)) * 64 + kb];
#pragma unroll
            for (int ni = 0; ni < 4; ++ni)
                bfr[ni] = *(const bf16x8*)&Bs[(wn + ni * 16 + (lane & 15)) * 64 + kb];
#pragma unroll
            for (int mi = 0; mi < 4; ++mi)
#pragma unroll
                for (int ni = 0; ni < 4; ++ni)
                    acc[mi][ni] = __builtin_amdgcn_mfma_f32_16x16x32_bf16(
                        af[mi], bfr[ni], acc[mi][ni], 0, 0, 0);
        }
        __syncthreads();
    }

    // epilogue: D col = lane&15, row = (lane>>4)*4 + r
#pragma unroll
    for (int ni = 0; ni < 4; ++ni) {
        int col = bn * 128 + wn + ni * 16 + (lane & 15);
        float bv = bias1 ? bias1[col] : 0.0f;
        if (bias2) bv += bias2[col];
#pragma unroll
        for (int mi = 0; mi < 4; ++mi) {
            int row = bm * 128 + wm + mi * 16 + (lane >> 4) * 4;
#pragma unroll
            for (int r = 0; r < 4; ++r)
                C[(size_t)(row + r) * N + col] = acc[mi][ni][r] + bv;
        }
    }
}

// ---------------- persistent recurrent kernel ----------------
// 256 WGs x 512 threads. WG owns 8 hidden units (32 gate rows).
// Wave w computes rows w*4..w*4+3; lane holds W_hh[row][c*512+lane*8+j] in regs.
__global__ __launch_bounds__(512) void lstm_rec_k(const float* __restrict__ Whh,
                                                  const float* __restrict__ xg,
                                                  unsigned short* __restrict__ hs,
                                                  unsigned* __restrict__ cnt) {
    const int wg = blockIdx.x;
    const int tid = threadIdx.x;
    const int wave = tid >> 6;
    const int lane = tid & 63;
    const int u0 = wg << 3;

    __shared__ float gbuf[32];

    float w[4][4][8];
#pragma unroll
    for (int rr = 0; rr < 4; ++rr) {
        const int rl = wave * 4 + rr;
        const int gate = rl >> 3, unit = rl & 7;
        const float* wrow = Whh + (size_t)(gate * HH + u0 + unit) * HH + lane * 8;
#pragma unroll
        for (int c = 0; c < 4; ++c) {
            float4 lo = *(const float4*)(wrow + c * 512);
            float4 hi = *(const float4*)(wrow + c * 512 + 4);
            w[rr][c][0] = lo.x; w[rr][c][1] = lo.y; w[rr][c][2] = lo.z; w[rr][c][3] = lo.w;
            w[rr][c][4] = hi.x; w[rr][c][5] = hi.y; w[rr][c][6] = hi.z; w[rr][c][7] = hi.w;
        }
    }

    float creg = 0.0f;
    const unsigned short* hsl = hs + lane * 8;

    for (int t = 0; t < TT; ++t) {
        float xgi = 0.f, xgf = 0.f, xgg = 0.f, xgo = 0.f;
        if (tid < 8) {
            const float* xr = xg + ((size_t)t << 13) + u0 + tid;
            xgi = xr[0]; xgf = xr[2048]; xgg = xr[4096]; xgo = xr[6144];
        }
        // h_{t-1}: 4 chunks of 8 bf16 per lane
        const uint4* hp = (const uint4*)(hsl + ((size_t)t << 11));
        uint4 hv0 = hp[0], hv1 = hp[64], hv2 = hp[128], hv3 = hp[192];

        float acc0 = 0.f, acc1 = 0.f, acc2 = 0.f, acc3 = 0.f;
        {
            float h8[8];
            unpack8(hv0, h8);
#pragma unroll
            for (int j = 0; j < 8; ++j) {
                acc0 = fmaf(w[0][0][j], h8[j], acc0);
                acc1 = fmaf(w[1][0][j], h8[j], acc1);
                acc2 = fmaf(w[2][0][j], h8[j], acc2);
                acc3 = fmaf(w[3][0][j], h8[j], acc3);
            }
            unpack8(hv1, h8);
#pragma unroll
            for (int j = 0; j < 8; ++j) {
                acc0 = fmaf(w[0][1][j], h8[j], acc0);
                acc1 = fmaf(w[1][1][j], h8[j], acc1);
                acc2 = fmaf(w[2][1][j], h8[j], acc2);
                acc3 = fmaf(w[3][1][j], h8[j], acc3);
            }
            unpack8(hv2, h8);
#pragma unroll
            for (int j = 0; j < 8; ++j) {
                acc0 = fmaf(w[0][2][j], h8[j], acc0);
                acc1 = fmaf(w[1][2][j], h8[j], acc1);
                acc2 = fmaf(w[2][2][j], h8[j], acc2);
                acc3 = fmaf(w[3][2][j], h8[j], acc3);
            }
            unpack8(hv3, h8);
#pragma unroll
            for (int j = 0; j < 8; ++j) {
                acc0 = fmaf(w[0][3][j], h8[j], acc0);
                acc1 = fmaf(w[1][3][j], h8[j], acc1);
                acc2 = fmaf(w[2][3][j], h8[j], acc2);
                acc3 = fmaf(w[3][3][j], h8[j], acc3);
            }
        }
#pragma unroll
        for (int off = 32; off >= 1; off >>= 1) {
            acc0 += __shfl_xor(acc0, off, 64);
            acc1 += __shfl_xor(acc1, off, 64);
            acc2 += __shfl_xor(acc2, off, 64);
            acc3 += __shfl_xor(acc3, off, 64);
        }
        if (lane == 0) {
            gbuf[wave * 4 + 0] = acc0;
            gbuf[wave * 4 + 1] = acc1;
            gbuf[wave * 4 + 2] = acc2;
            gbuf[wave * 4 + 3] = acc3;
        }
        __syncthreads();
        if (tid < 8) {
            float gi = gbuf[tid] + xgi;
            float gf = gbuf[8 + tid] + xgf;
            float gg = gbuf[16 + tid] + xgg;
            float go = gbuf[24 + tid] + xgo;
            float si = 1.0f / (1.0f + __expf(-gi));
            float sf = 1.0f / (1.0f + __expf(-gf));
            float tg = tanhf(gg);
            float so = 1.0f / (1.0f + __expf(-go));
            creg = sf * creg + si * tg;
            float h = so * tanhf(creg);
            hs[((size_t)(t + 1) << 11) + u0 + tid] = f2bf(h);
            __threadfence();
        }
        __syncthreads();
        if (tid == 0) {
            const unsigned b = wg & 7;
            unsigned v = __hip_atomic_fetch_add(&cnt[b * 32], 1u, __ATOMIC_ACQ_REL,
                                                __HIP_MEMORY_SCOPE_AGENT);
            if (v == 32u * (unsigned)(t + 1) - 1u) {
                unsigned s = __hip_atomic_fetch_add(&cnt[256], 1u, __ATOMIC_ACQ_REL,
                                                    __HIP_MEMORY_SCOPE_AGENT);
                if (s == 8u * (unsigned)(t + 1) - 1u) {
                    __hip_atomic_store(&cnt[288], (unsigned)(t + 1), __ATOMIC_RELEASE,
                                       __HIP_MEMORY_SCOPE_AGENT);
                }
            }
            while (__hip_atomic_load(&cnt[288], __ATOMIC_ACQUIRE,
                                     __HIP_MEMORY_SCOPE_AGENT) < (unsigned)(t + 1))
                __builtin_amdgcn_s_sleep(1);
        }
        __syncthreads();
    }
}

// ---------------- log-softmax over rows of [T][TAGS] ----------------
__global__ __launch_bounds__(256) void lsm_k(const float* __restrict__ tag,
                                             float* __restrict__ out) {
    const int row = blockIdx.x, tid = threadIdx.x;
    const int wave = tid >> 6, lane = tid & 63;
    const float* p = tag + ((size_t)row << 10);
    float v0 = p[tid], v1 = p[tid + 256], v2 = p[tid + 512], v3 = p[tid + 768];
    float m = fmaxf(fmaxf(v0, v1), fmaxf(v2, v3));
#pragma unroll
    for (int off = 32; off >= 1; off >>= 1) m = fmaxf(m, __shfl_xor(m, off, 64));
    __shared__ float redm[4];
    __shared__ float reds[4];
    if (lane == 0) redm[wave] = m;
    __syncthreads();
    m = fmaxf(fmaxf(redm[0], redm[1]), fmaxf(redm[2], redm[3]));
    float s = __expf(v0 - m) + __expf(v1 - m) + __expf(v2 - m) + __expf(v3 - m);
#pragma unroll
    for (int off = 32; off >= 1; off >>= 1) s += __shfl_xor(s, off, 64);
    if (lane == 0) reds[wave] = s;
    __syncthreads();
    s = reds[0] + reds[1] + reds[2] + reds[3];
    float lse = m + __logf(s);
    float* o = out + ((size_t)row << 10);
    o[tid] = v0 - lse; o[tid + 256] = v1 - lse;
    o[tid + 512] = v2 - lse; o[tid + 768] = v3 - lse;
}

extern "C" void kernel_launch(void* const* d_in, const int* in_sizes, int n_in,
                              void* d_out, int out_size, void* d_ws, size_t ws_size,
                              hipStream_t stream) {
    const float* x    = (const float*)d_in[0];
    const float* Wih  = (const float*)d_in[1];
    const float* Whh  = (const float*)d_in[2];
    const float* bih  = (const float*)d_in[3];
    const float* bhh  = (const float*)d_in[4];
    const float* Wout = (const float*)d_in[5];
    const float* bout = (const float*)d_in[6];
    float* out = (float*)d_out;

    // workspace carve
    char* ws = (char*)d_ws;
    size_t off = 0;
    unsigned* cnt = (unsigned*)(ws + off); off += 4096;
    unsigned short* hs = (unsigned short*)(ws + off); off += (size_t)(TT + 1) * HH * 2;      // 8.0 MiB
    off = (off + 1023) & ~(size_t)1023;
    float* xg = (float*)(ws + off); off += (size_t)TT * G4 * 4;                               // 64 MiB
    unsigned short* xbf = (unsigned short*)(ws + off); off += (size_t)TT * DD * 2;            // 4 MiB
    unsigned short* wihbf = (unsigned short*)(ws + off); off += (size_t)G4 * DD * 2;          // 16 MiB
    unsigned short* woutbf = (unsigned short*)(ws + off); off += (size_t)TAGS_ * HH * 2;      // 4 MiB
    float* tag = (float*)(ws + off); off += (size_t)TT * TAGS_ * 4;                           // 8 MiB

    // reset barrier counters + zero h_{-1}
    hipMemsetAsync(cnt, 0, 4096, stream);
    hipMemsetAsync(hs, 0, (size_t)HH * 2, stream);

    // converts
    cvt_bf16_k<<<(TT * DD) / 1024, 256, 0, stream>>>(x, xbf, TT * DD);
    cvt_bf16_k<<<(G4 * DD) / 1024, 256, 0, stream>>>(Wih, wihbf, G4 * DD);
    cvt_bf16_k<<<(TAGS_ * HH) / 1024, 256, 0, stream>>>(Wout, woutbf, TAGS_ * HH);

    // phase A: xg[T][4H] = x @ W_ih^T + (b_ih + b_hh)
    gemm_bt_k<<<dim3(G4 / 128, TT / 128), 256, 0, stream>>>(xbf, wihbf, xg, bih, bhh,
                                                            TT, G4, DD);

    // phase B: recurrence (cooperative persistent kernel)
    {
        const float* whh_p = Whh;
        const float* xg_p = xg;
        unsigned short* hs_p = hs;
        unsigned* cnt_p = cnt;
        void* args[] = {(void*)&whh_p, (void*)&xg_p, (void*)&hs_p, (void*)&cnt_p};
        hipLaunchCooperativeKernel((const void*)lstm_rec_k, dim3(256), dim3(512), args, 0,
                                   stream);
    }

    // phase C: tag[T][TAGS] = hs @ W_out^T + b_out   (hs rows 1..T)
    gemm_bt_k<<<dim3(TAGS_ / 128, TT / 128), 256, 0, stream>>>(hs + HH, woutbf, tag, bout,
                                                               nullptr, TT, TAGS_, HH);

    // log-softmax
    lsm_k<<<TT, 256, 0, stream>>>(tag, out);
}

// Round 2
// 13832.291 us; speedup vs baseline: 2.6620x; 2.6620x over previous
//
#include <hip/hip_runtime.h>
#include <hip/hip_bf16.h>

// Problem dims
#define TT    2048
#define DD    1024
#define HH    2048
#define TAGS_ 1024
#define G4    8192   // 4*H

typedef float f32x4 __attribute__((ext_vector_type(4)));
typedef __bf16 bf16x8 __attribute__((ext_vector_type(8)));

__device__ __forceinline__ unsigned short f2bf(float f) {
    unsigned u = __float_as_uint(f);
    unsigned r = (u + 0x7fffu + ((u >> 16) & 1u)) >> 16;
    return (unsigned short)r;
}

__device__ __forceinline__ void unpack8(uint4 v, float* h) {
    h[0] = __uint_as_float(v.x << 16); h[1] = __uint_as_float(v.x & 0xffff0000u);
    h[2] = __uint_as_float(v.y << 16); h[3] = __uint_as_float(v.y & 0xffff0000u);
    h[4] = __uint_as_float(v.z << 16); h[5] = __uint_as_float(v.z & 0xffff0000u);
    h[6] = __uint_as_float(v.w << 16); h[7] = __uint_as_float(v.w & 0xffff0000u);
}

// ---------------- fp32 -> bf16 convert ----------------
__global__ __launch_bounds__(256) void cvt_bf16_k(const float* __restrict__ in,
                                                  unsigned short* __restrict__ out, int n) {
    int i = (blockIdx.x * 256 + threadIdx.x) * 4;
    if (i < n) {
        float4 v = *(const float4*)(in + i);
        ushort4 o;
        o.x = f2bf(v.x); o.y = f2bf(v.y); o.z = f2bf(v.z); o.w = f2bf(v.w);
        *(ushort4*)(out + i) = o;
    }
}

// ---------------- bf16 MFMA GEMM: C[M][N] = A[M][K] * B[N][K]^T + bias ----------------
__global__ __launch_bounds__(256) void gemm_bt_k(const unsigned short* __restrict__ A,
                                                 const unsigned short* __restrict__ B,
                                                 float* __restrict__ C,
                                                 const float* __restrict__ bias1,
                                                 const float* __restrict__ bias2,
                                                 int M, int N, int K) {
    const int bn = blockIdx.x, bm = blockIdx.y;
    const int tid = threadIdx.x;
    const int wave = tid >> 6, lane = tid & 63;
    const int wm = (wave >> 1) * 64, wn = (wave & 1) * 64;

    __shared__ unsigned short As[128 * 64];
    __shared__ unsigned short Bs[128 * 64];

    f32x4 acc[4][4] = {};

    for (int k0 = 0; k0 < K; k0 += 64) {
#pragma unroll
        for (int i = 0; i < 4; ++i) {
            int bo = (tid + i * 256) * 16;
            int r = bo >> 7;
            int cb = bo & 127;
            *(uint4*)((char*)As + bo) =
                *(const uint4*)((const char*)(A + (size_t)(bm * 128 + r) * K + k0) + cb);
            *(uint4*)((char*)Bs + bo) =
                *(const uint4*)((const char*)(B + (size_t)(bn * 128 + r) * K + k0) + cb);
        }
        __syncthreads();
#pragma unroll
        for (int kk = 0; kk < 64; kk += 32) {
            int kb = kk + (lane >> 4) * 8;
            bf16x8 af[4], bfr[4];
#pragma unroll
            for (int mi = 0; mi < 4; ++mi)
                af[mi] = *(const bf16x8*)&As[(wm + mi * 16 + (lane & 15)) * 64 + kb];
#pragma unroll
            for (int ni = 0; ni < 4; ++ni)
                bfr[ni] = *(const bf16x8*)&Bs[(wn + ni * 16 + (lane & 15)) * 64 + kb];
#pragma unroll
            for (int mi = 0; mi < 4; ++mi)
#pragma unroll
                for (int ni = 0; ni < 4; ++ni)
                    acc[mi][ni] = __builtin_amdgcn_mfma_f32_16x16x32_bf16(
                        af[mi], bfr[ni], acc[mi][ni], 0, 0, 0);
        }
        __syncthreads();
    }

#pragma unroll
    for (int ni = 0; ni < 4; ++ni) {
        int col = bn * 128 + wn + ni * 16 + (lane & 15);
        float bv = bias1 ? bias1[col] : 0.0f;
        if (bias2) bv += bias2[col];
#pragma unroll
        for (int mi = 0; mi < 4; ++mi) {
            int row = bm * 128 + wm + mi * 16 + (lane >> 4) * 4;
#pragma unroll
            for (int r = 0; r < 4; ++r)
                C[(size_t)(row + r) * N + col] = acc[mi][ni][r] + bv;
        }
    }
}

// ---------------- persistent recurrent kernel ----------------
// 256 WGs x 512 threads. WG owns 8 hidden units; wave w owns unit u0+w (all
// 4 gate rows). Lane holds W_hh[gate][unit][c*512 + lane*8 + j] in regs.
// Cross-WG sync: per-WG packed flags, all sc0/sc1 write-through/bypass ops
// meeting at the Infinity Cache. No threadfence, no global RMW atomics.
__global__ __launch_bounds__(512) void lstm_rec_k(const float* __restrict__ Whh,
                                                  const float* __restrict__ xg,
                                                  unsigned short* __restrict__ hs,
                                                  unsigned* __restrict__ flags) {
    const int wg = blockIdx.x;
    const int tid = threadIdx.x;
    const int wave = tid >> 6;
    const int lane = tid & 63;
    const int u0 = wg << 3;
    const int unit = u0 + wave;   // global hidden unit owned by this wave

    __shared__ unsigned cnt_lds;
    if (tid == 0) cnt_lds = 0;

    // weights: w[gate][c][j] = Whh[gate*H + unit][c*512 + lane*8 + j]
    float w[4][4][8];
#pragma unroll
    for (int g = 0; g < 4; ++g) {
        const float* wrow = Whh + (size_t)(g * HH + unit) * HH + lane * 8;
#pragma unroll
        for (int c = 0; c < 4; ++c) {
            float4 lo = *(const float4*)(wrow + c * 512);
            float4 hi = *(const float4*)(wrow + c * 512 + 4);
            w[g][c][0] = lo.x; w[g][c][1] = lo.y; w[g][c][2] = lo.z; w[g][c][3] = lo.w;
            w[g][c][4] = hi.x; w[g][c][5] = hi.y; w[g][c][6] = hi.z; w[g][c][7] = hi.w;
        }
    }
    __syncthreads();

    float creg = 0.0f;
    const unsigned* pollp = flags + (lane << 2);   // 4 packed flags per lane

    for (int t = 0; t < TT; ++t) {
        // xg prefetch (lane 0 of each wave; independent of h_t)
        float xg0 = 0.f, xg1 = 0.f, xg2 = 0.f, xg3 = 0.f;
        if (lane == 0) {
            const float* xr = xg + ((size_t)t << 13) + unit;
            xg0 = xr[0]; xg1 = xr[2048]; xg2 = xr[4096]; xg3 = xr[6144];
        }

        // wait until all 256 WGs published hs[t]
        if (t > 0 && wave == 0) {
            for (;;) {
                uint4 f;
                asm volatile(
                    "global_load_dwordx4 %0, %1, off sc0 sc1\n\t"
                    "s_waitcnt vmcnt(0)"
                    : "=&v"(f) : "v"(pollp) : "memory");
                unsigned mn = f.x < f.y ? f.x : f.y;
                unsigned mn2 = f.z < f.w ? f.z : f.w;
                mn = mn < mn2 ? mn : mn2;
                if (__all((int)(mn >= (unsigned)t))) break;
                __builtin_amdgcn_s_sleep(1);
            }
        }
        __syncthreads();

        // h_t: 4 x 16B bypass loads (LLC-fresh; never cached in L1/L2)
        const char* hp = (const char*)hs + ((size_t)t << 12) + lane * 16;
        uint4 hv0, hv1, hv2, hv3;
        asm volatile(
            "global_load_dwordx4 %0, %4, off sc0 sc1\n\t"
            "global_load_dwordx4 %1, %4, off offset:1024 sc0 sc1\n\t"
            "global_load_dwordx4 %2, %4, off offset:2048 sc0 sc1\n\t"
            "global_load_dwordx4 %3, %4, off offset:3072 sc0 sc1\n\t"
            "s_waitcnt vmcnt(0)"
            : "=&v"(hv0), "=&v"(hv1), "=&v"(hv2), "=&v"(hv3)
            : "v"(hp) : "memory");

        float acc0 = 0.f, acc1 = 0.f, acc2 = 0.f, acc3 = 0.f;
        {
            float h8[8];
            unpack8(hv0, h8);
#pragma unroll
            for (int j = 0; j < 8; ++j) {
                acc0 = fmaf(w[0][0][j], h8[j], acc0);
                acc1 = fmaf(w[1][0][j], h8[j], acc1);
                acc2 = fmaf(w[2][0][j], h8[j], acc2);
                acc3 = fmaf(w[3][0][j], h8[j], acc3);
            }
            unpack8(hv1, h8);
#pragma unroll
            for (int j = 0; j < 8; ++j) {
                acc0 = fmaf(w[0][1][j], h8[j], acc0);
                acc1 = fmaf(w[1][1][j], h8[j], acc1);
                acc2 = fmaf(w[2][1][j], h8[j], acc2);
                acc3 = fmaf(w[3][1][j], h8[j], acc3);
            }
            unpack8(hv2, h8);
#pragma unroll
            for (int j = 0; j < 8; ++j) {
                acc0 = fmaf(w[0][2][j], h8[j], acc0);
                acc1 = fmaf(w[1][2][j], h8[j], acc1);
                acc2 = fmaf(w[2][2][j], h8[j], acc2);
                acc3 = fmaf(w[3][2][j], h8[j], acc3);
            }
            unpack8(hv3, h8);
#pragma unroll
            for (int j = 0; j < 8; ++j) {
                acc0 = fmaf(w[0][3][j], h8[j], acc0);
                acc1 = fmaf(w[1][3][j], h8[j], acc1);
                acc2 = fmaf(w[2][3][j], h8[j], acc2);
                acc3 = fmaf(w[3][3][j], h8[j], acc3);
            }
        }
#pragma unroll
        for (int off = 32; off >= 1; off >>= 1) {
            acc0 += __shfl_xor(acc0, off, 64);
            acc1 += __shfl_xor(acc1, off, 64);
            acc2 += __shfl_xor(acc2, off, 64);
            acc3 += __shfl_xor(acc3, off, 64);
        }

        if (lane == 0) {
            float gi = acc0 + xg0;
            float gf = acc1 + xg1;
            float gg = acc2 + xg2;
            float go = acc3 + xg3;
            float si = 1.0f / (1.0f + __expf(-gi));
            float sf = 1.0f / (1.0f + __expf(-gf));
            float tg = tanhf(gg);
            float so = 1.0f / (1.0f + __expf(-go));
            creg = sf * creg + si * tg;
            float h = so * tanhf(creg);
            unsigned hb = (unsigned)f2bf(h);

            unsigned short* hd = hs + (((size_t)(t + 1)) << 11) + unit;
            // publish h chunk (write-through to LLC), wait commit
            asm volatile(
                "global_store_short %0, %1, off sc0 sc1\n\t"
                "s_waitcnt vmcnt(0)"
                :: "v"(hd), "v"(hb) : "memory");
            // wave arrival; last of 8 waves publishes the WG flag
            unsigned old = atomicAdd(&cnt_lds, 1u);
            if (old == 8u * (unsigned)(t + 1) - 1u) {
                unsigned fv = (unsigned)(t + 1);
                const unsigned* fd = flags + wg;
                asm volatile(
                    "global_store_dword %0, %1, off sc0 sc1"
                    :: "v"(fd), "v"(fv) : "memory");
            }
        }
    }
}

// ---------------- log-softmax over rows of [T][TAGS] ----------------
__global__ __launch_bounds__(256) void lsm_k(const float* __restrict__ tag,
                                             float* __restrict__ out) {
    const int row = blockIdx.x, tid = threadIdx.x;
    const int wave = tid >> 6, lane = tid & 63;
    const float* p = tag + ((size_t)row << 10);
    float v0 = p[tid], v1 = p[tid + 256], v2 = p[tid + 512], v3 = p[tid + 768];
    float m = fmaxf(fmaxf(v0, v1), fmaxf(v2, v3));
#pragma unroll
    for (int off = 32; off >= 1; off >>= 1) m = fmaxf(m, __shfl_xor(m, off, 64));
    __shared__ float redm[4];
    __shared__ float reds[4];
    if (lane == 0) redm[wave] = m;
    __syncthreads();
    m = fmaxf(fmaxf(redm[0], redm[1]), fmaxf(redm[2], redm[3]));
    float s = __expf(v0 - m) + __expf(v1 - m) + __expf(v2 - m) + __expf(v3 - m);
#pragma unroll
    for (int off = 32; off >= 1; off >>= 1) s += __shfl_xor(s, off, 64);
    if (lane == 0) reds[wave] = s;
    __syncthreads();
    s = reds[0] + reds[1] + reds[2] + reds[3];
    float lse = m + __logf(s);
    float* o = out + ((size_t)row << 10);
    o[tid] = v0 - lse; o[tid + 256] = v1 - lse;
    o[tid + 512] = v2 - lse; o[tid + 768] = v3 - lse;
}

extern "C" void kernel_launch(void* const* d_in, const int* in_sizes, int n_in,
                              void* d_out, int out_size, void* d_ws, size_t ws_size,
                              hipStream_t stream) {
    const float* x    = (const float*)d_in[0];
    const float* Wih  = (const float*)d_in[1];
    const float* Whh  = (const float*)d_in[2];
    const float* bih  = (const float*)d_in[3];
    const float* bhh  = (const float*)d_in[4];
    const float* Wout = (const float*)d_in[5];
    const float* bout = (const float*)d_in[6];
    float* out = (float*)d_out;

    // workspace carve
    char* ws = (char*)d_ws;
    size_t off = 0;
    unsigned* flags = (unsigned*)(ws + off); off += 4096;
    unsigned short* hs = (unsigned short*)(ws + off); off += (size_t)(TT + 1) * HH * 2;
    off = (off + 1023) & ~(size_t)1023;
    float* xg = (float*)(ws + off); off += (size_t)TT * G4 * 4;
    unsigned short* xbf = (unsigned short*)(ws + off); off += (size_t)TT * DD * 2;
    unsigned short* wihbf = (unsigned short*)(ws + off); off += (size_t)G4 * DD * 2;
    unsigned short* woutbf = (unsigned short*)(ws + off); off += (size_t)TAGS_ * HH * 2;
    float* tag = (float*)(ws + off); off += (size_t)TT * TAGS_ * 4;

    // reset flags + zero h_0
    hipMemsetAsync(flags, 0, 4096, stream);
    hipMemsetAsync(hs, 0, (size_t)HH * 2, stream);

    // converts
    cvt_bf16_k<<<(TT * DD) / 1024, 256, 0, stream>>>(x, xbf, TT * DD);
    cvt_bf16_k<<<(G4 * DD) / 1024, 256, 0, stream>>>(Wih, wihbf, G4 * DD);
    cvt_bf16_k<<<(TAGS_ * HH) / 1024, 256, 0, stream>>>(Wout, woutbf, TAGS_ * HH);

    // phase A: xg[T][4H] = x @ W_ih^T + (b_ih + b_hh)
    gemm_bt_k<<<dim3(G4 / 128, TT / 128), 256, 0, stream>>>(xbf, wihbf, xg, bih, bhh,
                                                            TT, G4, DD);

    // phase B: recurrence (cooperative persistent kernel)
    {
        const float* whh_p = Whh;
        const float* xg_p = xg;
        unsigned short* hs_p = hs;
        unsigned* fl_p = flags;
        void* args[] = {(void*)&whh_p, (void*)&xg_p, (void*)&hs_p, (void*)&fl_p};
        hipLaunchCooperativeKernel((const void*)lstm_rec_k, dim3(256), dim3(512), args, 0,
                                   stream);
    }

    // phase C: tag[T][TAGS] = hs @ W_out^T + b_out
    gemm_bt_k<<<dim3(TAGS_ / 128, TT / 128), 256, 0, stream>>>(hs + HH, woutbf, tag, bout,
                                                               nullptr, TT, TAGS_, HH);

    // log-softmax
    lsm_k<<<TT, 256, 0, stream>>>(tag, out);
}

// Round 3
// 9807.967 us; speedup vs baseline: 3.7543x; 1.4103x over previous
//
#include <hip/hip_runtime.h>
#include <hip/hip_bf16.h>

// Problem dims
#define TT    2048
#define DD    1024
#define HH    2048
#define TAGS_ 1024
#define G4    8192   // 4*H

typedef float f32x4 __attribute__((ext_vector_type(4)));
typedef __bf16 bf16x8 __attribute__((ext_vector_type(8)));

__device__ __forceinline__ unsigned short f2bf(float f) {
    unsigned u = __float_as_uint(f);
    unsigned r = (u + 0x7fffu + ((u >> 16) & 1u)) >> 16;
    return (unsigned short)r;
}

// ---------------- fp32 -> bf16 convert ----------------
__global__ __launch_bounds__(256) void cvt_bf16_k(const float* __restrict__ in,
                                                  unsigned short* __restrict__ out, int n) {
    int i = (blockIdx.x * 256 + threadIdx.x) * 4;
    if (i < n) {
        float4 v = *(const float4*)(in + i);
        ushort4 o;
        o.x = f2bf(v.x); o.y = f2bf(v.y); o.z = f2bf(v.z); o.w = f2bf(v.w);
        *(ushort4*)(out + i) = o;
    }
}

// ---------------- extract low 16 bits (tagged word -> bf16) ----------------
__global__ __launch_bounds__(256) void cvt_lo16_k(const unsigned* __restrict__ in,
                                                  unsigned short* __restrict__ out, int n) {
    int i = (blockIdx.x * 256 + threadIdx.x) * 4;
    if (i < n) {
        uint4 v = *(const uint4*)(in + i);
        ushort4 o;
        o.x = (unsigned short)v.x; o.y = (unsigned short)v.y;
        o.z = (unsigned short)v.z; o.w = (unsigned short)v.w;
        *(ushort4*)(out + i) = o;
    }
}

// ---------------- bf16 MFMA GEMM: C[M][N] = A[M][K] * B[N][K]^T + bias ----------------
__global__ __launch_bounds__(256) void gemm_bt_k(const unsigned short* __restrict__ A,
                                                 const unsigned short* __restrict__ B,
                                                 float* __restrict__ C,
                                                 const float* __restrict__ bias1,
                                                 const float* __restrict__ bias2,
                                                 int M, int N, int K) {
    const int bn = blockIdx.x, bm = blockIdx.y;
    const int tid = threadIdx.x;
    const int wave = tid >> 6, lane = tid & 63;
    const int wm = (wave >> 1) * 64, wn = (wave & 1) * 64;

    __shared__ unsigned short As[128 * 64];
    __shared__ unsigned short Bs[128 * 64];

    f32x4 acc[4][4] = {};

    for (int k0 = 0; k0 < K; k0 += 64) {
#pragma unroll
        for (int i = 0; i < 4; ++i) {
            int bo = (tid + i * 256) * 16;
            int r = bo >> 7;
            int cb = bo & 127;
            *(uint4*)((char*)As + bo) =
                *(const uint4*)((const char*)(A + (size_t)(bm * 128 + r) * K + k0) + cb);
            *(uint4*)((char*)Bs + bo) =
                *(const uint4*)((const char*)(B + (size_t)(bn * 128 + r) * K + k0) + cb);
        }
        __syncthreads();
#pragma unroll
        for (int kk = 0; kk < 64; kk += 32) {
            int kb = kk + (lane >> 4) * 8;
            bf16x8 af[4], bfr[4];
#pragma unroll
            for (int mi = 0; mi < 4; ++mi)
                af[mi] = *(const bf16x8*)&As[(wm + mi * 16 + (lane & 15)) * 64 + kb];
#pragma unroll
            for (int ni = 0; ni < 4; ++ni)
                bfr[ni] = *(const bf16x8*)&Bs[(wn + ni * 16 + (lane & 15)) * 64 + kb];
#pragma unroll
            for (int mi = 0; mi < 4; ++mi)
#pragma unroll
                for (int ni = 0; ni < 4; ++ni)
                    acc[mi][ni] = __builtin_amdgcn_mfma_f32_16x16x32_bf16(
                        af[mi], bfr[ni], acc[mi][ni], 0, 0, 0);
        }
        __syncthreads();
    }

#pragma unroll
    for (int ni = 0; ni < 4; ++ni) {
        int col = bn * 128 + wn + ni * 16 + (lane & 15);
        float bv = bias1 ? bias1[col] : 0.0f;
        if (bias2) bv += bias2[col];
#pragma unroll
        for (int mi = 0; mi < 4; ++mi) {
            int row = bm * 128 + wm + mi * 16 + (lane >> 4) * 4;
#pragma unroll
            for (int r = 0; r < 4; ++r)
                C[(size_t)(row + r) * N + col] = acc[mi][ni][r] + bv;
        }
    }
}

// ---------------- persistent recurrent kernel ----------------
// 256 WGs x 512 threads, 1 WG/CU. Wave w of WG b owns hidden unit b*8+w.
// Lane holds W_hh[gate][unit][k*256 + lane*4 + j] in registers (128 VGPRs).
// Sync: tagged h words hs32[t][u] = (t<<16) | bf16(h_t[u]). Producers do a
// single fire-and-forget sc0/sc1 dword store; consumers poll the data itself
// (tag==t), stage to LDS ping-pong, one __syncthreads, compute from LDS.
// No flags, no fences, no atomics, no grid barrier.
__global__ __launch_bounds__(512, 2) void lstm_rec_k(const float* __restrict__ Whh,
                                                     const float* __restrict__ xg,
                                                     unsigned* __restrict__ hs32) {
    const int tid = threadIdx.x;
    const int wave = tid >> 6;
    const int lane = tid & 63;
    const int unit = (blockIdx.x << 3) + wave;   // hidden unit owned by this wave

    __shared__ unsigned hbuf[2][2048];           // ping-pong staged h_t (tagged words)

    // weights in registers: w[g][k][j] = Whh[g*H + unit][k*256 + lane*4 + j]
    f32x4 w[4][8];
#pragma unroll
    for (int g = 0; g < 4; ++g) {
        const float* wrow = Whh + (size_t)(g * HH + unit) * HH + (lane << 2);
#pragma unroll
        for (int k = 0; k < 8; ++k)
            w[g][k] = *(const f32x4*)(wrow + (k << 8));
    }

    float creg = 0.0f;

    for (int t = 0; t < TT; ++t) {
        // xg prefetch (independent of h_t; issued before the poll)
        float xg0 = 0.f, xg1 = 0.f, xg2 = 0.f, xg3 = 0.f;
        if (lane == 0) {
            const float* xr = xg + ((size_t)t << 13) + unit;
            xg0 = xr[0]; xg1 = xr[2048]; xg2 = xr[4096]; xg3 = xr[6144];
        }

        // poll own 256-word slice of h_t (1 dwordx4 per lane, LLC bypass)
        const unsigned* pp = hs32 + ((size_t)t << 11) + (wave << 8) + (lane << 2);
        uint4 hv;
        const unsigned tu = (unsigned)t;
        for (;;) {
            asm volatile(
                "global_load_dwordx4 %0, %1, off sc0 sc1\n\t"
                "s_waitcnt vmcnt(0)"
                : "=&v"(hv) : "v"(pp) : "memory");
            int ok = (hv.x >> 16) == tu && (hv.y >> 16) == tu &&
                     (hv.z >> 16) == tu && (hv.w >> 16) == tu;
            if (__all(ok)) break;
            __builtin_amdgcn_s_sleep(1);
        }

        // stage slice to LDS (contiguous 16B per lane: conflict-free)
        *(uint4*)&hbuf[t & 1][(wave << 8) + (lane << 2)] = hv;
        __syncthreads();

        // dot products over full h_t from LDS: element h[k*256 + lane*4 + j]
        float acc0 = 0.f, acc1 = 0.f, acc2 = 0.f, acc3 = 0.f;
#pragma unroll
        for (int k = 0; k < 8; ++k) {
            uint4 hw = *(const uint4*)&hbuf[t & 1][(k << 8) + (lane << 2)];
            float h0 = __uint_as_float(hw.x << 16);
            float h1 = __uint_as_float(hw.y << 16);
            float h2 = __uint_as_float(hw.z << 16);
            float h3 = __uint_as_float(hw.w << 16);
            acc0 = fmaf(w[0][k][0], h0, acc0); acc1 = fmaf(w[1][k][0], h0, acc1);
            acc2 = fmaf(w[2][k][0], h0, acc2); acc3 = fmaf(w[3][k][0], h0, acc3);
            acc0 = fmaf(w[0][k][1], h1, acc0); acc1 = fmaf(w[1][k][1], h1, acc1);
            acc2 = fmaf(w[2][k][1], h1, acc2); acc3 = fmaf(w[3][k][1], h1, acc3);
            acc0 = fmaf(w[0][k][2], h2, acc0); acc1 = fmaf(w[1][k][2], h2, acc1);
            acc2 = fmaf(w[2][k][2], h2, acc2); acc3 = fmaf(w[3][k][2], h2, acc3);
            acc0 = fmaf(w[0][k][3], h3, acc0); acc1 = fmaf(w[1][k][3], h3, acc1);
            acc2 = fmaf(w[2][k][3], h3, acc2); acc3 = fmaf(w[3][k][3], h3, acc3);
        }
#pragma unroll
        for (int off = 32; off >= 1; off >>= 1) {
            acc0 += __shfl_xor(acc0, off, 64);
            acc1 += __shfl_xor(acc1, off, 64);
            acc2 += __shfl_xor(acc2, off, 64);
            acc3 += __shfl_xor(acc3, off, 64);
        }

        if (lane == 0) {
            float gi = acc0 + xg0;
            float gf = acc1 + xg1;
            float gg = acc2 + xg2;
            float go = acc3 + xg3;
            // sigmoid / tanh via v_exp (exp2-based fast path)
            float ei = __expf(-gi), ef = __expf(-gf), eo = __expf(-go);
            float eg = __expf(-2.0f * gg);
            float si = 1.0f / (1.0f + ei);
            float sf = 1.0f / (1.0f + ef);
            float so = 1.0f / (1.0f + eo);
            float tg = 2.0f / (1.0f + eg) - 1.0f;
            creg = sf * creg + si * tg;
            float ec = __expf(-2.0f * creg);
            float th = 2.0f / (1.0f + ec) - 1.0f;
            float h = so * th;
            unsigned word = ((unsigned)(t + 1) << 16) | (unsigned)f2bf(h);
            unsigned* hd = hs32 + (((size_t)(t + 1)) << 11) + unit;
            // fire-and-forget publish (commits at LLC; consumers poll the data)
            asm volatile("global_store_dword %0, %1, off sc0 sc1"
                         :: "v"(hd), "v"(word) : "memory");
        }
    }
}

// ---------------- log-softmax over rows of [T][TAGS] ----------------
__global__ __launch_bounds__(256) void lsm_k(const float* __restrict__ tag,
                                             float* __restrict__ out) {
    const int row = blockIdx.x, tid = threadIdx.x;
    const int wave = tid >> 6, lane = tid & 63;
    const float* p = tag + ((size_t)row << 10);
    float v0 = p[tid], v1 = p[tid + 256], v2 = p[tid + 512], v3 = p[tid + 768];
    float m = fmaxf(fmaxf(v0, v1), fmaxf(v2, v3));
#pragma unroll
    for (int off = 32; off >= 1; off >>= 1) m = fmaxf(m, __shfl_xor(m, off, 64));
    __shared__ float redm[4];
    __shared__ float reds[4];
    if (lane == 0) redm[wave] = m;
    __syncthreads();
    m = fmaxf(fmaxf(redm[0], redm[1]), fmaxf(redm[2], redm[3]));
    float s = __expf(v0 - m) + __expf(v1 - m) + __expf(v2 - m) + __expf(v3 - m);
#pragma unroll
    for (int off = 32; off >= 1; off >>= 1) s += __shfl_xor(s, off, 64);
    if (lane == 0) reds[wave] = s;
    __syncthreads();
    s = reds[0] + reds[1] + reds[2] + reds[3];
    float lse = m + __logf(s);
    float* o = out + ((size_t)row << 10);
    o[tid] = v0 - lse; o[tid + 256] = v1 - lse;
    o[tid + 512] = v2 - lse; o[tid + 768] = v3 - lse;
}

extern "C" void kernel_launch(void* const* d_in, const int* in_sizes, int n_in,
                              void* d_out, int out_size, void* d_ws, size_t ws_size,
                              hipStream_t stream) {
    const float* x    = (const float*)d_in[0];
    const float* Wih  = (const float*)d_in[1];
    const float* Whh  = (const float*)d_in[2];
    const float* bih  = (const float*)d_in[3];
    const float* bhh  = (const float*)d_in[4];
    const float* Wout = (const float*)d_in[5];
    const float* bout = (const float*)d_in[6];
    float* out = (float*)d_out;

    // workspace carve (with deliberate aliasing; all uses stream-ordered):
    //   hs32 [16.8MB] -- tagged h words; ALSO aliased by `tag` (phase C output,
    //                    written only after post-pass has consumed hs32)
    //   xg   [64MB]
    //   xbf  [4MB]
    //   wihbf[16MB]   -- ALSO aliased by `hs` bf16 (written by post-pass after
    //                    phase A is done with wihbf)
    //   woutbf[4MB]
    char* ws = (char*)d_ws;
    size_t off = 0;
    unsigned* hs32 = (unsigned*)(ws + off); off += (size_t)(TT + 1) * HH * 4;   // 16.8MB
    float* tag = (float*)hs32;                                                   // alias
    float* xg = (float*)(ws + off); off += (size_t)TT * G4 * 4;                  // 64MB
    unsigned short* xbf = (unsigned short*)(ws + off); off += (size_t)TT * DD * 2;
    unsigned short* wihbf = (unsigned short*)(ws + off); off += (size_t)G4 * DD * 2;
    unsigned short* hs = (unsigned short*)wihbf;                                 // alias
    unsigned short* woutbf = (unsigned short*)(ws + off); off += (size_t)TAGS_ * HH * 2;

    // clear ALL tags every call (h_0 row = tag 0 + value 0, exactly what t=0
    // needs; also prevents timed replays from observing stale-tag shortcuts)
    hipMemsetAsync(hs32, 0, (size_t)(TT + 1) * HH * 4, stream);

    // converts
    cvt_bf16_k<<<(TT * DD) / 1024, 256, 0, stream>>>(x, xbf, TT * DD);
    cvt_bf16_k<<<(G4 * DD) / 1024, 256, 0, stream>>>(Wih, wihbf, G4 * DD);
    cvt_bf16_k<<<(TAGS_ * HH) / 1024, 256, 0, stream>>>(Wout, woutbf, TAGS_ * HH);

    // phase A: xg[T][4H] = x @ W_ih^T + (b_ih + b_hh)
    gemm_bt_k<<<dim3(G4 / 128, TT / 128), 256, 0, stream>>>(xbf, wihbf, xg, bih, bhh,
                                                            TT, G4, DD);

    // phase B: recurrence (persistent dataflow kernel, 1 WG/CU)
    {
        const float* whh_p = Whh;
        const float* xg_p = xg;
        unsigned* hs32_p = hs32;
        void* args[] = {(void*)&whh_p, (void*)&xg_p, (void*)&hs32_p};
        hipLaunchCooperativeKernel((const void*)lstm_rec_k, dim3(256), dim3(512), args, 0,
                                   stream);
    }

    // post-pass: hs[t][u] (bf16) = low16(hs32[t+1][u]), t = 0..T-1
    cvt_lo16_k<<<(TT * HH) / 1024, 256, 0, stream>>>(hs32 + HH, hs, TT * HH);

    // phase C: tag[T][TAGS] = hs @ W_out^T + b_out
    gemm_bt_k<<<dim3(TAGS_ / 128, TT / 128), 256, 0, stream>>>(hs, woutbf, tag, bout,
                                                               nullptr, TT, TAGS_, HH);

    // log-softmax
    lsm_k<<<TT, 256, 0, stream>>>(tag, out);
}

// Round 4
// 6093.890 us; speedup vs baseline: 6.0424x; 1.6095x over previous
//
#include <hip/hip_runtime.h>
#include <hip/hip_bf16.h>

// Problem dims
#define TT    2048
#define DD    1024
#define HH    2048
#define TAGS_ 1024
#define G4    8192   // 4*H

typedef float f32x4 __attribute__((ext_vector_type(4)));
typedef __bf16 bf16x8 __attribute__((ext_vector_type(8)));
typedef _Float16 f16x2 __attribute__((ext_vector_type(2)));
typedef _Float16 f16x4 __attribute__((ext_vector_type(4)));
typedef unsigned u32x2 __attribute__((ext_vector_type(2)));

__device__ __forceinline__ unsigned short f2bf(float f) {
    unsigned u = __float_as_uint(f);
    unsigned r = (u + 0x7fffu + ((u >> 16) & 1u)) >> 16;
    return (unsigned short)r;
}

__device__ __forceinline__ f16x2 u2h(unsigned u) {
    return __builtin_bit_cast(f16x2, u);
}

#if __has_builtin(__builtin_amdgcn_fdot2)
#define FDOT2(a, b, c) __builtin_amdgcn_fdot2((a), (b), (c), false)
#else
__device__ __forceinline__ float FDOT2(f16x2 a, f16x2 b, float c) {
    return fmaf((float)a.x, (float)b.x, fmaf((float)a.y, (float)b.y, c));
}
#endif

// ---------------- fp32 -> bf16 convert ----------------
__global__ __launch_bounds__(256) void cvt_bf16_k(const float* __restrict__ in,
                                                  unsigned short* __restrict__ out, int n) {
    int i = (blockIdx.x * 256 + threadIdx.x) * 4;
    if (i < n) {
        float4 v = *(const float4*)(in + i);
        ushort4 o;
        o.x = f2bf(v.x); o.y = f2bf(v.y); o.z = f2bf(v.z); o.w = f2bf(v.w);
        *(ushort4*)(out + i) = o;
    }
}

// ---------------- fp32 -> fp16 convert ----------------
__global__ __launch_bounds__(256) void cvt_f16_k(const float* __restrict__ in,
                                                 _Float16* __restrict__ out, int n) {
    int i = (blockIdx.x * 256 + threadIdx.x) * 4;
    if (i < n) {
        float4 v = *(const float4*)(in + i);
        f16x4 o;
        o.x = (_Float16)v.x; o.y = (_Float16)v.y;
        o.z = (_Float16)v.z; o.w = (_Float16)v.w;
        *(f16x4*)(out + i) = o;
    }
}

// ------------- tagged word (f16 in low16) -> bf16 -------------
__global__ __launch_bounds__(256) void cvt_lo16f_k(const unsigned* __restrict__ in,
                                                   unsigned short* __restrict__ out, int n) {
    int i = (blockIdx.x * 256 + threadIdx.x) * 4;
    if (i < n) {
        uint4 v = *(const uint4*)(in + i);
        ushort4 o;
        o.x = f2bf((float)__builtin_bit_cast(_Float16, (unsigned short)(v.x & 0xffff)));
        o.y = f2bf((float)__builtin_bit_cast(_Float16, (unsigned short)(v.y & 0xffff)));
        o.z = f2bf((float)__builtin_bit_cast(_Float16, (unsigned short)(v.z & 0xffff)));
        o.w = f2bf((float)__builtin_bit_cast(_Float16, (unsigned short)(v.w & 0xffff)));
        *(ushort4*)(out + i) = o;
    }
}

// ---------------- bf16 MFMA GEMM: C[M][N] = A[M][K] * B[N][K]^T + bias ----------------
// out_f16 != 0 -> store _Float16, else float.
__global__ __launch_bounds__(256) void gemm_bt_k(const unsigned short* __restrict__ A,
                                                 const unsigned short* __restrict__ B,
                                                 void* __restrict__ Cv,
                                                 const float* __restrict__ bias1,
                                                 const float* __restrict__ bias2,
                                                 int M, int N, int K, int out_f16) {
    const int bn = blockIdx.x, bm = blockIdx.y;
    const int tid = threadIdx.x;
    const int wave = tid >> 6, lane = tid & 63;
    const int wm = (wave >> 1) * 64, wn = (wave & 1) * 64;

    __shared__ unsigned short As[128 * 64];
    __shared__ unsigned short Bs[128 * 64];

    f32x4 acc[4][4] = {};

    for (int k0 = 0; k0 < K; k0 += 64) {
#pragma unroll
        for (int i = 0; i < 4; ++i) {
            int bo = (tid + i * 256) * 16;
            int r = bo >> 7;
            int cb = bo & 127;
            *(uint4*)((char*)As + bo) =
                *(const uint4*)((const char*)(A + (size_t)(bm * 128 + r) * K + k0) + cb);
            *(uint4*)((char*)Bs + bo) =
                *(const uint4*)((const char*)(B + (size_t)(bn * 128 + r) * K + k0) + cb);
        }
        __syncthreads();
#pragma unroll
        for (int kk = 0; kk < 64; kk += 32) {
            int kb = kk + (lane >> 4) * 8;
            bf16x8 af[4], bfr[4];
#pragma unroll
            for (int mi = 0; mi < 4; ++mi)
                af[mi] = *(const bf16x8*)&As[(wm + mi * 16 + (lane & 15)) * 64 + kb];
#pragma unroll
            for (int ni = 0; ni < 4; ++ni)
                bfr[ni] = *(const bf16x8*)&Bs[(wn + ni * 16 + (lane & 15)) * 64 + kb];
#pragma unroll
            for (int mi = 0; mi < 4; ++mi)
#pragma unroll
                for (int ni = 0; ni < 4; ++ni)
                    acc[mi][ni] = __builtin_amdgcn_mfma_f32_16x16x32_bf16(
                        af[mi], bfr[ni], acc[mi][ni], 0, 0, 0);
        }
        __syncthreads();
    }

#pragma unroll
    for (int ni = 0; ni < 4; ++ni) {
        int col = bn * 128 + wn + ni * 16 + (lane & 15);
        float bv = bias1 ? bias1[col] : 0.0f;
        if (bias2) bv += bias2[col];
#pragma unroll
        for (int mi = 0; mi < 4; ++mi) {
            int row = bm * 128 + wm + mi * 16 + (lane >> 4) * 4;
#pragma unroll
            for (int r = 0; r < 4; ++r) {
                float v = acc[mi][ni][r] + bv;
                if (out_f16)
                    ((_Float16*)Cv)[(size_t)(row + r) * N + col] = (_Float16)v;
                else
                    ((float*)Cv)[(size_t)(row + r) * N + col] = v;
            }
        }
    }
}

// ---------------- persistent recurrent kernel ----------------
// 256 WGs x 512 threads, 1 WG/CU. Wave w of WG b owns hidden unit b*8+w.
// Weights: W_hh in fp16, 64 VGPRs/lane, pinned via opaque empty-asm so the
// compiler cannot sink the loads back into the loop (round-3 failure mode).
// Sync: tagged words hs32[t][u] = (t<<16) | f16(h_t[u]); producers do one
// fire-and-forget sc0/sc1 dword store; consumers poll their slice, stage
// packed f16 pairs to LDS ping-pong, one barrier, dot2 from LDS.
__global__ __launch_bounds__(512, 2) void lstm_rec_k(const _Float16* __restrict__ Whh16,
                                                     const _Float16* __restrict__ xg,
                                                     unsigned* __restrict__ hs32) {
    const int tid = threadIdx.x;
    const int wave = tid >> 6;
    const int lane = tid & 63;
    const int unit = (blockIdx.x << 3) + wave;   // hidden unit owned by this wave

    __shared__ unsigned hpk[2][1024];            // packed f16 pairs of h_t (ping-pong)

    // weight rows for the 4 gates of this unit
    const _Float16* wr0 = Whh16 + ((size_t)(0 * HH) + unit) * HH + (lane << 2);
    const _Float16* wr1 = Whh16 + ((size_t)(1 * HH) + unit) * HH + (lane << 2);
    const _Float16* wr2 = Whh16 + ((size_t)(2 * HH) + unit) * HH + (lane << 2);
    const _Float16* wr3 = Whh16 + ((size_t)(3 * HH) + unit) * HH + (lane << 2);

#define LDW(v, p, k) u32x2 v = *(const u32x2*)((p) + (k) * 256)
    LDW(w00, wr0, 0); LDW(w01, wr0, 1); LDW(w02, wr0, 2); LDW(w03, wr0, 3);
    LDW(w04, wr0, 4); LDW(w05, wr0, 5); LDW(w06, wr0, 6); LDW(w07, wr0, 7);
    LDW(w10, wr1, 0); LDW(w11, wr1, 1); LDW(w12, wr1, 2); LDW(w13, wr1, 3);
    LDW(w14, wr1, 4); LDW(w15, wr1, 5); LDW(w16, wr1, 6); LDW(w17, wr1, 7);
    LDW(w20, wr2, 0); LDW(w21, wr2, 1); LDW(w22, wr2, 2); LDW(w23, wr2, 3);
    LDW(w24, wr2, 4); LDW(w25, wr2, 5); LDW(w26, wr2, 6); LDW(w27, wr2, 7);
    LDW(w30, wr3, 0); LDW(w31, wr3, 1); LDW(w32, wr3, 2); LDW(w33, wr3, 3);
    LDW(w34, wr3, 4); LDW(w35, wr3, 5); LDW(w36, wr3, 6); LDW(w37, wr3, 7);
#undef LDW

    // Pin: values become asm-defined -> cannot be rematerialized from memory.
#define PIN(a, b, c, d) asm volatile("" : "+v"(a), "+v"(b), "+v"(c), "+v"(d))
    PIN(w00, w01, w02, w03); PIN(w04, w05, w06, w07);
    PIN(w10, w11, w12, w13); PIN(w14, w15, w16, w17);
    PIN(w20, w21, w22, w23); PIN(w24, w25, w26, w27);
    PIN(w30, w31, w32, w33); PIN(w34, w35, w36, w37);
#undef PIN

    float creg = 0.0f;

    for (int t = 0; t < TT; ++t) {
        const int buf = t & 1;

        // xg prefetch (independent of h_t; issued before the poll)
        float xg0 = 0.f, xg1 = 0.f, xg2 = 0.f, xg3 = 0.f;
        if (lane == 0) {
            const _Float16* xr = xg + ((size_t)t << 13) + unit;
            xg0 = (float)xr[0]; xg1 = (float)xr[2048];
            xg2 = (float)xr[4096]; xg3 = (float)xr[6144];
        }

        // poll own 256-word slice of h_t (1 dwordx4 per lane, LLC bypass)
        const unsigned* pp = hs32 + ((size_t)t << 11) + (wave << 8) + (lane << 2);
        uint4 hv;
        const unsigned tu = (unsigned)t;
        for (;;) {
            asm volatile(
                "global_load_dwordx4 %0, %1, off sc0 sc1\n\t"
                "s_waitcnt vmcnt(0)"
                : "=&v"(hv) : "v"(pp));
            int ok = (hv.x >> 16) == tu && (hv.y >> 16) == tu &&
                     (hv.z >> 16) == tu && (hv.w >> 16) == tu;
            if (__all(ok)) break;
            __builtin_amdgcn_s_sleep(1);
        }

        // stage packed f16 pairs to LDS (strip tags): 2 dwords per lane
        unsigned plo = (hv.x & 0xffffu) | (hv.y << 16);
        unsigned phi = (hv.z & 0xffffu) | (hv.w << 16);
        u32x2 pk; pk.x = plo; pk.y = phi;
        *(u32x2*)&hpk[buf][(wave << 7) + (lane << 1)] = pk;
        __syncthreads();

        // 4 gate dot-products over full h_t via v_dot2_f32_f16
        float acc0 = 0.f, acc1 = 0.f, acc2 = 0.f, acc3 = 0.f;
#define DOTK(kk, WA, WB, WC, WD) do {                                        \
        u32x2 hp = *(const u32x2*)&hpk[buf][((kk) << 7) + (lane << 1)];      \
        f16x2 hlo = u2h(hp.x), hhi = u2h(hp.y);                              \
        acc0 = FDOT2(u2h(WA.x), hlo, acc0); acc0 = FDOT2(u2h(WA.y), hhi, acc0); \
        acc1 = FDOT2(u2h(WB.x), hlo, acc1); acc1 = FDOT2(u2h(WB.y), hhi, acc1); \
        acc2 = FDOT2(u2h(WC.x), hlo, acc2); acc2 = FDOT2(u2h(WC.y), hhi, acc2); \
        acc3 = FDOT2(u2h(WD.x), hlo, acc3); acc3 = FDOT2(u2h(WD.y), hhi, acc3); \
    } while (0)
        DOTK(0, w00, w10, w20, w30);
        DOTK(1, w01, w11, w21, w31);
        DOTK(2, w02, w12, w22, w32);
        DOTK(3, w03, w13, w23, w33);
        DOTK(4, w04, w14, w24, w34);
        DOTK(5, w05, w15, w25, w35);
        DOTK(6, w06, w16, w26, w36);
        DOTK(7, w07, w17, w27, w37);
#undef DOTK

#pragma unroll
        for (int off = 32; off >= 1; off >>= 1) {
            acc0 += __shfl_xor(acc0, off, 64);
            acc1 += __shfl_xor(acc1, off, 64);
            acc2 += __shfl_xor(acc2, off, 64);
            acc3 += __shfl_xor(acc3, off, 64);
        }

        if (lane == 0) {
            float gi = acc0 + xg0;
            float gf = acc1 + xg1;
            float gg = acc2 + xg2;
            float go = acc3 + xg3;
            float ei = __expf(-gi), ef = __expf(-gf), eo = __expf(-go);
            float eg = __expf(-2.0f * gg);
            float si = 1.0f / (1.0f + ei);
            float sf = 1.0f / (1.0f + ef);
            float so = 1.0f / (1.0f + eo);
            float tg = 2.0f / (1.0f + eg) - 1.0f;
            creg = sf * creg + si * tg;
            float ec = __expf(-2.0f * creg);
            float th = 2.0f / (1.0f + ec) - 1.0f;
            float h = so * th;
            _Float16 fh = (_Float16)h;
            unsigned word = ((unsigned)(t + 1) << 16) |
                            (unsigned)__builtin_bit_cast(unsigned short, fh);
            unsigned* hd = hs32 + (((size_t)(t + 1)) << 11) + unit;
            asm volatile("global_store_dword %0, %1, off sc0 sc1"
                         :: "v"(hd), "v"(word));
        }
    }
}

// ---------------- log-softmax over rows of [T][TAGS] ----------------
__global__ __launch_bounds__(256) void lsm_k(const float* __restrict__ tag,
                                             float* __restrict__ out) {
    const int row = blockIdx.x, tid = threadIdx.x;
    const int wave = tid >> 6, lane = tid & 63;
    const float* p = tag + ((size_t)row << 10);
    float v0 = p[tid], v1 = p[tid + 256], v2 = p[tid + 512], v3 = p[tid + 768];
    float m = fmaxf(fmaxf(v0, v1), fmaxf(v2, v3));
#pragma unroll
    for (int off = 32; off >= 1; off >>= 1) m = fmaxf(m, __shfl_xor(m, off, 64));
    __shared__ float redm[4];
    __shared__ float reds[4];
    if (lane == 0) redm[wave] = m;
    __syncthreads();
    m = fmaxf(fmaxf(redm[0], redm[1]), fmaxf(redm[2], redm[3]));
    float s = __expf(v0 - m) + __expf(v1 - m) + __expf(v2 - m) + __expf(v3 - m);
#pragma unroll
    for (int off = 32; off >= 1; off >>= 1) s += __shfl_xor(s, off, 64);
    if (lane == 0) reds[wave] = s;
    __syncthreads();
    s = reds[0] + reds[1] + reds[2] + reds[3];
    float lse = m + __logf(s);
    float* o = out + ((size_t)row << 10);
    o[tid] = v0 - lse; o[tid + 256] = v1 - lse;
    o[tid + 512] = v2 - lse; o[tid + 768] = v3 - lse;
}

extern "C" void kernel_launch(void* const* d_in, const int* in_sizes, int n_in,
                              void* d_out, int out_size, void* d_ws, size_t ws_size,
                              hipStream_t stream) {
    const float* x    = (const float*)d_in[0];
    const float* Wih  = (const float*)d_in[1];
    const float* Whh  = (const float*)d_in[2];
    const float* bih  = (const float*)d_in[3];
    const float* bhh  = (const float*)d_in[4];
    const float* Wout = (const float*)d_in[5];
    const float* bout = (const float*)d_in[6];
    float* out = (float*)d_out;

    // workspace carve with time-sliced aliasing (all uses stream-ordered):
    //  A: hs32 [16.8MB] tagged h words; aliased by `tag` in phase C
    //  B: xg   [32MB]   f16 gate preacts
    //  C: 33.6MB region:
    //     pre-GEMM-A: xbf @C+0 (4MB), wihbf @C+4MB (16MB)
    //     pre-rec   : Whh16 @C+0 (33.6MB)   [cvt AFTER phase A]
    //     post-rec  : woutbf @C+0 (4MB), hs bf16 @C+4MB (8MB)
    char* ws = (char*)d_ws;
    size_t off = 0;
    unsigned* hs32 = (unsigned*)(ws + off); off += (size_t)(TT + 1) * HH * 4;   // 16.8MB
    float* tag = (float*)hs32;                                                   // alias
    _Float16* xg = (_Float16*)(ws + off); off += (size_t)TT * G4 * 2;            // 32MB
    char* C = ws + off; off += (size_t)G4 * HH * 2;                              // 33.6MB
    unsigned short* xbf    = (unsigned short*)(C);
    unsigned short* wihbf  = (unsigned short*)(C + ((size_t)TT * DD * 2) * 2);   // C+4MB
    _Float16* Whh16        = (_Float16*)(C);
    unsigned short* woutbf = (unsigned short*)(C);
    unsigned short* hs     = (unsigned short*)(C + (size_t)4 * 1024 * 1024);     // C+4MB

    // clear ALL tags every call (h_0 = tag 0 + f16 zero; also prevents timed
    // replays from observing stale tags)
    hipMemsetAsync(hs32, 0, (size_t)(TT + 1) * HH * 4, stream);

    // converts for phase A
    cvt_bf16_k<<<(TT * DD) / 1024, 256, 0, stream>>>(x, xbf, TT * DD);
    cvt_bf16_k<<<(G4 * DD) / 1024, 256, 0, stream>>>(Wih, wihbf, G4 * DD);

    // phase A: xg[T][4H] (f16) = x @ W_ih^T + (b_ih + b_hh)
    gemm_bt_k<<<dim3(G4 / 128, TT / 128), 256, 0, stream>>>(xbf, wihbf, (void*)xg,
                                                            bih, bhh, TT, G4, DD, 1);

    // W_hh -> f16 (overwrites xbf/wihbf region — phase A is done with them)
    cvt_f16_k<<<(G4 * HH) / 1024, 256, 0, stream>>>(Whh, Whh16, G4 * HH);

    // phase B: recurrence (persistent dataflow kernel, 1 WG/CU)
    {
        const _Float16* whh_p = Whh16;
        const _Float16* xg_p = xg;
        unsigned* hs32_p = hs32;
        void* args[] = {(void*)&whh_p, (void*)&xg_p, (void*)&hs32_p};
        hipLaunchCooperativeKernel((const void*)lstm_rec_k, dim3(256), dim3(512), args, 0,
                                   stream);
    }

    // converts for phase C (overwrite Whh16 region — recurrence is done)
    cvt_bf16_k<<<(TAGS_ * HH) / 1024, 256, 0, stream>>>(Wout, woutbf, TAGS_ * HH);
    cvt_lo16f_k<<<(TT * HH) / 1024, 256, 0, stream>>>(hs32 + HH, hs, TT * HH);

    // phase C: tag[T][TAGS] = hs @ W_out^T + b_out  (tag aliases hs32; the
    // post-pass above already consumed hs32)
    gemm_bt_k<<<dim3(TAGS_ / 128, TT / 128), 256, 0, stream>>>(hs, woutbf, (void*)tag,
                                                               bout, nullptr,
                                                               TT, TAGS_, HH, 0);

    // log-softmax
    lsm_k<<<TT, 256, 0, stream>>>(tag, out);
}

// Round 5
// 5467.805 us; speedup vs baseline: 6.7343x; 1.1145x over previous
//
#include <hip/hip_runtime.h>
#include <hip/hip_bf16.h>

// Problem dims
#define TT    2048
#define DD    1024
#define HH    2048
#define TAGS_ 1024
#define G4    8192   // 4*H

typedef float f32x4 __attribute__((ext_vector_type(4)));
typedef __bf16 bf16x8 __attribute__((ext_vector_type(8)));
typedef _Float16 f16x2 __attribute__((ext_vector_type(2)));
typedef _Float16 f16x4 __attribute__((ext_vector_type(4)));
typedef unsigned u32x2 __attribute__((ext_vector_type(2)));

__device__ __forceinline__ unsigned short f2bf(float f) {
    unsigned u = __float_as_uint(f);
    unsigned r = (u + 0x7fffu + ((u >> 16) & 1u)) >> 16;
    return (unsigned short)r;
}

__device__ __forceinline__ f16x2 u2h(unsigned u) {
    return __builtin_bit_cast(f16x2, u);
}

#if __has_builtin(__builtin_amdgcn_fdot2)
#define FDOT2(a, b, c) __builtin_amdgcn_fdot2((a), (b), (c), false)
#else
__device__ __forceinline__ float FDOT2(f16x2 a, f16x2 b, float c) {
    return fmaf((float)a.x, (float)b.x, fmaf((float)a.y, (float)b.y, c));
}
#endif

// ---------------- fp32 -> bf16 convert ----------------
__global__ __launch_bounds__(256) void cvt_bf16_k(const float* __restrict__ in,
                                                  unsigned short* __restrict__ out, int n) {
    int i = (blockIdx.x * 256 + threadIdx.x) * 4;
    if (i < n) {
        float4 v = *(const float4*)(in + i);
        ushort4 o;
        o.x = f2bf(v.x); o.y = f2bf(v.y); o.z = f2bf(v.z); o.w = f2bf(v.w);
        *(ushort4*)(out + i) = o;
    }
}

// ---------------- fp32 -> fp16 convert ----------------
__global__ __launch_bounds__(256) void cvt_f16_k(const float* __restrict__ in,
                                                 _Float16* __restrict__ out, int n) {
    int i = (blockIdx.x * 256 + threadIdx.x) * 4;
    if (i < n) {
        float4 v = *(const float4*)(in + i);
        f16x4 o;
        o.x = (_Float16)v.x; o.y = (_Float16)v.y;
        o.z = (_Float16)v.z; o.w = (_Float16)v.w;
        *(f16x4*)(out + i) = o;
    }
}

// ------------- tagged word (f16 in low16) -> bf16 -------------
__global__ __launch_bounds__(256) void cvt_lo16f_k(const unsigned* __restrict__ in,
                                                   unsigned short* __restrict__ out, int n) {
    int i = (blockIdx.x * 256 + threadIdx.x) * 4;
    if (i < n) {
        uint4 v = *(const uint4*)(in + i);
        ushort4 o;
        o.x = f2bf((float)__builtin_bit_cast(_Float16, (unsigned short)(v.x & 0xffff)));
        o.y = f2bf((float)__builtin_bit_cast(_Float16, (unsigned short)(v.y & 0xffff)));
        o.z = f2bf((float)__builtin_bit_cast(_Float16, (unsigned short)(v.z & 0xffff)));
        o.w = f2bf((float)__builtin_bit_cast(_Float16, (unsigned short)(v.w & 0xffff)));
        *(ushort4*)(out + i) = o;
    }
}

// ---------------- bf16 MFMA GEMM: C[M][N] = A[M][K] * B[N][K]^T + bias ----------------
// out_f16 != 0 -> store _Float16, else float.
__global__ __launch_bounds__(256) void gemm_bt_k(const unsigned short* __restrict__ A,
                                                 const unsigned short* __restrict__ B,
                                                 void* __restrict__ Cv,
                                                 const float* __restrict__ bias1,
                                                 const float* __restrict__ bias2,
                                                 int M, int N, int K, int out_f16) {
    const int bn = blockIdx.x, bm = blockIdx.y;
    const int tid = threadIdx.x;
    const int wave = tid >> 6, lane = tid & 63;
    const int wm = (wave >> 1) * 64, wn = (wave & 1) * 64;

    __shared__ unsigned short As[128 * 64];
    __shared__ unsigned short Bs[128 * 64];

    f32x4 acc[4][4] = {};

    for (int k0 = 0; k0 < K; k0 += 64) {
#pragma unroll
        for (int i = 0; i < 4; ++i) {
            int bo = (tid + i * 256) * 16;
            int r = bo >> 7;
            int cb = bo & 127;
            *(uint4*)((char*)As + bo) =
                *(const uint4*)((const char*)(A + (size_t)(bm * 128 + r) * K + k0) + cb);
            *(uint4*)((char*)Bs + bo) =
                *(const uint4*)((const char*)(B + (size_t)(bn * 128 + r) * K + k0) + cb);
        }
        __syncthreads();
#pragma unroll
        for (int kk = 0; kk < 64; kk += 32) {
            int kb = kk + (lane >> 4) * 8;
            bf16x8 af[4], bfr[4];
#pragma unroll
            for (int mi = 0; mi < 4; ++mi)
                af[mi] = *(const bf16x8*)&As[(wm + mi * 16 + (lane & 15)) * 64 + kb];
#pragma unroll
            for (int ni = 0; ni < 4; ++ni)
                bfr[ni] = *(const bf16x8*)&Bs[(wn + ni * 16 + (lane & 15)) * 64 + kb];
#pragma unroll
            for (int mi = 0; mi < 4; ++mi)
#pragma unroll
                for (int ni = 0; ni < 4; ++ni)
                    acc[mi][ni] = __builtin_amdgcn_mfma_f32_16x16x32_bf16(
                        af[mi], bfr[ni], acc[mi][ni], 0, 0, 0);
        }
        __syncthreads();
    }

#pragma unroll
    for (int ni = 0; ni < 4; ++ni) {
        int col = bn * 128 + wn + ni * 16 + (lane & 15);
        float bv = bias1 ? bias1[col] : 0.0f;
        if (bias2) bv += bias2[col];
#pragma unroll
        for (int mi = 0; mi < 4; ++mi) {
            int row = bm * 128 + wm + mi * 16 + (lane >> 4) * 4;
#pragma unroll
            for (int r = 0; r < 4; ++r) {
                float v = acc[mi][ni][r] + bv;
                if (out_f16)
                    ((_Float16*)Cv)[(size_t)(row + r) * N + col] = (_Float16)v;
                else
                    ((float*)Cv)[(size_t)(row + r) * N + col] = v;
            }
        }
    }
}

// ---------------- persistent recurrent kernel ----------------
// 256 WGs x 512 threads, 1 WG/CU. Wave w of WG b owns hidden unit b*8+w.
// W_hh fp16, 64 dwords/lane pinned in AGPRs (asm "+a") — regalloc cannot be
// pressured into spilling the AGPR class (round-4 failure: "+v" pin spilled
// to scratch, 128 KB/CU/step reloads from L2).
// Sync: tagged words hs32[t][u] = (t<<16) | f16(h_t[u]); producers do one
// fire-and-forget sc0/sc1 dword store; consumers poll their slice, stage
// packed f16 pairs to LDS ping-pong, one barrier, dot2 from LDS.
__global__ __launch_bounds__(512, 2) void lstm_rec_k(const _Float16* __restrict__ Whh16,
                                                     const _Float16* __restrict__ xg,
                                                     unsigned* __restrict__ hs32) {
    const int tid = threadIdx.x;
    const int wave = tid >> 6;
    const int lane = tid & 63;
    const int unit = (blockIdx.x << 3) + wave;   // hidden unit owned by this wave

    __shared__ unsigned hpk[2][1024];            // packed f16 pairs of h_t (ping-pong)

    // weights: W[g][k][p] = dword p of Whh16[g*H + unit][k*256 + lane*4 ..+3]
    unsigned W[4][8][2];
#pragma unroll
    for (int g = 0; g < 4; ++g) {
        const _Float16* wr = Whh16 + ((size_t)(g * HH) + unit) * HH + (lane << 2);
#pragma unroll
        for (int k = 0; k < 8; ++k) {
            u32x2 v = *(const u32x2*)(wr + (k << 8));
            W[g][k][0] = v.x; W[g][k][1] = v.y;
        }
    }
    // Pin into AGPRs: values become asm-defined in the 'a' class. No other
    // AGPR pressure exists -> they stay resident for the whole kernel.
#pragma unroll
    for (int g = 0; g < 4; ++g)
#pragma unroll
        for (int k = 0; k < 8; ++k)
            asm volatile("" : "+a"(W[g][k][0]), "+a"(W[g][k][1]));

    float creg = 0.0f;

    // xg prefetch pipeline: values for step t loaded during step t-1
    float xg0 = 0.f, xg1 = 0.f, xg2 = 0.f, xg3 = 0.f;
    if (lane == 0) {
        const _Float16* xr = xg + unit;
        xg0 = (float)xr[0]; xg1 = (float)xr[2048];
        xg2 = (float)xr[4096]; xg3 = (float)xr[6144];
    }

    for (int t = 0; t < TT; ++t) {
        const int buf = t & 1;

        // issue next step's xg loads early (hide HBM latency under this step)
        float nx0 = 0.f, nx1 = 0.f, nx2 = 0.f, nx3 = 0.f;
        if (lane == 0 && t + 1 < TT) {
            const _Float16* xr = xg + ((size_t)(t + 1) << 13) + unit;
            nx0 = (float)xr[0]; nx1 = (float)xr[2048];
            nx2 = (float)xr[4096]; nx3 = (float)xr[6144];
        }

        // poll own 256-word slice of h_t (1 dwordx4 per lane, LLC bypass)
        const unsigned* pp = hs32 + ((size_t)t << 11) + (wave << 8) + (lane << 2);
        uint4 hv;
        const unsigned tu = (unsigned)t;
        for (;;) {
            asm volatile(
                "global_load_dwordx4 %0, %1, off sc0 sc1\n\t"
                "s_waitcnt vmcnt(0)"
                : "=&v"(hv) : "v"(pp));
            int ok = (hv.x >> 16) == tu && (hv.y >> 16) == tu &&
                     (hv.z >> 16) == tu && (hv.w >> 16) == tu;
            if (__all(ok)) break;
            __builtin_amdgcn_s_sleep(1);
        }

        // stage packed f16 pairs to LDS (strip tags): 2 dwords per lane
        unsigned plo = (hv.x & 0xffffu) | (hv.y << 16);
        unsigned phi = (hv.z & 0xffffu) | (hv.w << 16);
        u32x2 pk; pk.x = plo; pk.y = phi;
        *(u32x2*)&hpk[buf][(wave << 7) + (lane << 1)] = pk;
        __syncthreads();

        // 4 gate dot-products over full h_t via v_dot2_f32_f16
        float acc0 = 0.f, acc1 = 0.f, acc2 = 0.f, acc3 = 0.f;
#define DOTK(kk) do {                                                          \
        u32x2 hp = *(const u32x2*)&hpk[buf][((kk) << 7) + (lane << 1)];        \
        f16x2 hlo = u2h(hp.x), hhi = u2h(hp.y);                                \
        acc0 = FDOT2(u2h(W[0][kk][0]), hlo, acc0);                             \
        acc0 = FDOT2(u2h(W[0][kk][1]), hhi, acc0);                             \
        acc1 = FDOT2(u2h(W[1][kk][0]), hlo, acc1);                             \
        acc1 = FDOT2(u2h(W[1][kk][1]), hhi, acc1);                             \
        acc2 = FDOT2(u2h(W[2][kk][0]), hlo, acc2);                             \
        acc2 = FDOT2(u2h(W[2][kk][1]), hhi, acc2);                             \
        acc3 = FDOT2(u2h(W[3][kk][0]), hlo, acc3);                             \
        acc3 = FDOT2(u2h(W[3][kk][1]), hhi, acc3);                             \
    } while (0)
        DOTK(0); DOTK(1); DOTK(2); DOTK(3);
        DOTK(4); DOTK(5); DOTK(6); DOTK(7);
#undef DOTK

#pragma unroll
        for (int off = 32; off >= 1; off >>= 1) {
            acc0 += __shfl_xor(acc0, off, 64);
            acc1 += __shfl_xor(acc1, off, 64);
            acc2 += __shfl_xor(acc2, off, 64);
            acc3 += __shfl_xor(acc3, off, 64);
        }

        if (lane == 0) {
            float gi = acc0 + xg0;
            float gf = acc1 + xg1;
            float gg = acc2 + xg2;
            float go = acc3 + xg3;
            float ei = __expf(-gi), ef = __expf(-gf), eo = __expf(-go);
            float eg = __expf(-2.0f * gg);
            float si = 1.0f / (1.0f + ei);
            float sf = 1.0f / (1.0f + ef);
            float so = 1.0f / (1.0f + eo);
            float tg = 2.0f / (1.0f + eg) - 1.0f;
            creg = sf * creg + si * tg;
            float ec = __expf(-2.0f * creg);
            float th = 2.0f / (1.0f + ec) - 1.0f;
            float h = so * th;
            _Float16 fh = (_Float16)h;
            unsigned word = ((unsigned)(t + 1) << 16) |
                            (unsigned)__builtin_bit_cast(unsigned short, fh);
            unsigned* hd = hs32 + (((size_t)(t + 1)) << 11) + unit;
            asm volatile("global_store_dword %0, %1, off sc0 sc1"
                         :: "v"(hd), "v"(word));
        }
        // rotate xg pipeline
        xg0 = nx0; xg1 = nx1; xg2 = nx2; xg3 = nx3;
    }
}

// ---------------- log-softmax over rows of [T][TAGS] ----------------
__global__ __launch_bounds__(256) void lsm_k(const float* __restrict__ tag,
                                             float* __restrict__ out) {
    const int row = blockIdx.x, tid = threadIdx.x;
    const int wave = tid >> 6, lane = tid & 63;
    const float* p = tag + ((size_t)row << 10);
    float v0 = p[tid], v1 = p[tid + 256], v2 = p[tid + 512], v3 = p[tid + 768];
    float m = fmaxf(fmaxf(v0, v1), fmaxf(v2, v3));
#pragma unroll
    for (int off = 32; off >= 1; off >>= 1) m = fmaxf(m, __shfl_xor(m, off, 64));
    __shared__ float redm[4];
    __shared__ float reds[4];
    if (lane == 0) redm[wave] = m;
    __syncthreads();
    m = fmaxf(fmaxf(redm[0], redm[1]), fmaxf(redm[2], redm[3]));
    float s = __expf(v0 - m) + __expf(v1 - m) + __expf(v2 - m) + __expf(v3 - m);
#pragma unroll
    for (int off = 32; off >= 1; off >>= 1) s += __shfl_xor(s, off, 64);
    if (lane == 0) reds[wave] = s;
    __syncthreads();
    s = reds[0] + reds[1] + reds[2] + reds[3];
    float lse = m + __logf(s);
    float* o = out + ((size_t)row << 10);
    o[tid] = v0 - lse; o[tid + 256] = v1 - lse;
    o[tid + 512] = v2 - lse; o[tid + 768] = v3 - lse;
}

extern "C" void kernel_launch(void* const* d_in, const int* in_sizes, int n_in,
                              void* d_out, int out_size, void* d_ws, size_t ws_size,
                              hipStream_t stream) {
    const float* x    = (const float*)d_in[0];
    const float* Wih  = (const float*)d_in[1];
    const float* Whh  = (const float*)d_in[2];
    const float* bih  = (const float*)d_in[3];
    const float* bhh  = (const float*)d_in[4];
    const float* Wout = (const float*)d_in[5];
    const float* bout = (const float*)d_in[6];
    float* out = (float*)d_out;

    // workspace carve with time-sliced aliasing (all uses stream-ordered):
    //  A: hs32 [16.8MB] tagged h words; aliased by `tag` in phase C
    //  B: xg   [32MB]   f16 gate preacts
    //  C: 33.6MB region:
    //     pre-GEMM-A: xbf @C+0 (4MB), wihbf @C+4MB (16MB)
    //     pre-rec   : Whh16 @C+0 (33.6MB)   [cvt AFTER phase A]
    //     post-rec  : woutbf @C+0 (4MB), hs bf16 @C+4MB (8MB)
    char* ws = (char*)d_ws;
    size_t off = 0;
    unsigned* hs32 = (unsigned*)(ws + off); off += (size_t)(TT + 1) * HH * 4;   // 16.8MB
    float* tag = (float*)hs32;                                                   // alias
    _Float16* xg = (_Float16*)(ws + off); off += (size_t)TT * G4 * 2;            // 32MB
    char* C = ws + off; off += (size_t)G4 * HH * 2;                              // 33.6MB
    unsigned short* xbf    = (unsigned short*)(C);
    unsigned short* wihbf  = (unsigned short*)(C + ((size_t)TT * DD * 2) * 2);   // C+4MB
    _Float16* Whh16        = (_Float16*)(C);
    unsigned short* woutbf = (unsigned short*)(C);
    unsigned short* hs     = (unsigned short*)(C + (size_t)4 * 1024 * 1024);     // C+4MB

    // clear ALL tags every call (h_0 = tag 0 + f16 zero; also prevents timed
    // replays from observing stale tags)
    hipMemsetAsync(hs32, 0, (size_t)(TT + 1) * HH * 4, stream);

    // converts for phase A
    cvt_bf16_k<<<(TT * DD) / 1024, 256, 0, stream>>>(x, xbf, TT * DD);
    cvt_bf16_k<<<(G4 * DD) / 1024, 256, 0, stream>>>(Wih, wihbf, G4 * DD);

    // phase A: xg[T][4H] (f16) = x @ W_ih^T + (b_ih + b_hh)
    gemm_bt_k<<<dim3(G4 / 128, TT / 128), 256, 0, stream>>>(xbf, wihbf, (void*)xg,
                                                            bih, bhh, TT, G4, DD, 1);

    // W_hh -> f16 (overwrites xbf/wihbf region — phase A is done with them)
    cvt_f16_k<<<(G4 * HH) / 1024, 256, 0, stream>>>(Whh, Whh16, G4 * HH);

    // phase B: recurrence (persistent dataflow kernel, 1 WG/CU)
    {
        const _Float16* whh_p = Whh16;
        const _Float16* xg_p = xg;
        unsigned* hs32_p = hs32;
        void* args[] = {(void*)&whh_p, (void*)&xg_p, (void*)&hs32_p};
        hipLaunchCooperativeKernel((const void*)lstm_rec_k, dim3(256), dim3(512), args, 0,
                                   stream);
    }

    // converts for phase C (overwrite Whh16 region — recurrence is done)
    cvt_bf16_k<<<(TAGS_ * HH) / 1024, 256, 0, stream>>>(Wout, woutbf, TAGS_ * HH);
    cvt_lo16f_k<<<(TT * HH) / 1024, 256, 0, stream>>>(hs32 + HH, hs, TT * HH);

    // phase C: tag[T][TAGS] = hs @ W_out^T + b_out  (tag aliases hs32; the
    // post-pass above already consumed hs32)
    gemm_bt_k<<<dim3(TAGS_ / 128, TT / 128), 256, 0, stream>>>(hs, woutbf, (void*)tag,
                                                               bout, nullptr,
                                                               TT, TAGS_, HH, 0);

    // log-softmax
    lsm_k<<<TT, 256, 0, stream>>>(tag, out);
}